// Round 1
// baseline (496.421 us; speedup 1.0000x reference)
//
#include <hip/hip_runtime.h>
#include <cstddef>

// Problem constants
#define NN 64     // NX = NY = T = 64
#define MK 12     // retained kz modes (0..11)
#define MP 24     // packed kx / ky modes (0..11, 52..63)
#define CH 16     // channels

__device__ __forceinline__ void build_tw(float* twc, float* tws, int tid, int nthreads) {
    for (int m = tid; m < 64; m += nthreads) {
        float ang = 6.283185307179586f * (float)m / 64.0f;
        twc[m] = cosf(ang);
        tws[m] = sinf(ang);
    }
}

// ---------------------------------------------------------------------------
// 1) forward DFT over t: x[b,ch,x,y,t] (real) -> Z1[(b*CH+ch)*64+x][kz][y] (complex)
//    block = (b*CH+ch)*64 + x ; 8192 blocks x 256 threads
__global__ __launch_bounds__(256) void k_fwd_t(const float* __restrict__ x,
                                               float2* __restrict__ z1) {
    __shared__ float xs[64 * 65];        // padded to kill bank conflicts
    __shared__ float twc[64], tws[64];
    int tid = threadIdx.x;
    int blk = blockIdx.x;
    build_tw(twc, tws, tid, 256);
    const float* src = x + (size_t)blk * 4096;
    for (int i = tid; i < 4096; i += 256) {
        int yy = i >> 6, tt = i & 63;
        xs[yy * 65 + tt] = src[i];
    }
    __syncthreads();
    float2* dst = z1 + (size_t)blk * (MK * 64);
    for (int idx = tid; idx < 64 * MK; idx += 256) {
        int yy = idx / MK, k = idx % MK;
        const float* row = xs + yy * 65;
        float re = 0.f, im = 0.f;
        int m = 0;
        for (int t = 0; t < 64; ++t) {
            float v = row[t];
            re += v * twc[m];      // e^{-i theta} = (cos, -sin)
            im -= v * tws[m];
            m = (m + k) & 63;
        }
        dst[k * 64 + yy] = make_float2(re, im);
    }
}

// ---------------------------------------------------------------------------
// 2) forward DFT over y: Z1[blk][kz][y] -> Z2[(bc*24+ky)][kz][x]
//    block = bc*64 + x ; 8192 blocks x 256 threads
__global__ __launch_bounds__(256) void k_fwd_y(const float2* __restrict__ z1,
                                               float2* __restrict__ z2) {
    __shared__ float2 zs[12 * 65];
    __shared__ float twc[64], tws[64];
    int tid = threadIdx.x;
    int blk = blockIdx.x;
    int xx = blk & 63, bc = blk >> 6;
    build_tw(twc, tws, tid, 256);
    const float2* src = z1 + (size_t)blk * (MK * 64);
    for (int i = tid; i < MK * 64; i += 256) {
        int kz = i >> 6, yy = i & 63;
        zs[kz * 65 + yy] = src[i];
    }
    __syncthreads();
    for (int idx = tid; idx < MP * MK; idx += 256) {
        int ky = idx / MK, kz = idx % MK;
        int kya = (ky < 12) ? ky : (ky + 40);   // packed hi modes: 52..63
        const float2* rowz = zs + kz * 65;
        float re = 0.f, im = 0.f;
        int m = 0;
        for (int yy2 = 0; yy2 < 64; ++yy2) {
            float2 a = rowz[yy2];
            float c = twc[m], s = tws[m];
            re += a.x * c + a.y * s;            // a * (c - i s)
            im += a.y * c - a.x * s;
            m = (m + kya) & 63;
        }
        z2[((size_t)(bc * MP + ky) * MK + kz) * 64 + xx] = make_float2(re, im);
    }
}

// ---------------------------------------------------------------------------
// 3) forward DFT over x: Z2[(bc*24+ky)][kz][x] -> Z3[b][kx][ky][kz][ci]
//    block = bc*24 + ky ; 3072 blocks x 256 threads
__global__ __launch_bounds__(256) void k_fwd_x(const float2* __restrict__ z2,
                                               float2* __restrict__ z3) {
    __shared__ float2 zs[12 * 65];
    __shared__ float twc[64], tws[64];
    int tid = threadIdx.x;
    int blk = blockIdx.x;
    int ky = blk % MP, bc = blk / MP;
    int b = bc >> 4, ci = bc & 15;
    build_tw(twc, tws, tid, 256);
    const float2* src = z2 + (size_t)blk * (MK * 64);
    for (int i = tid; i < MK * 64; i += 256) {
        int kz = i >> 6, xx2 = i & 63;
        zs[kz * 65 + xx2] = src[i];
    }
    __syncthreads();
    for (int idx = tid; idx < MP * MK; idx += 256) {
        int kx = idx / MK, kz = idx % MK;
        int kxa = (kx < 12) ? kx : (kx + 40);
        const float2* rowz = zs + kz * 65;
        float re = 0.f, im = 0.f;
        int m = 0;
        for (int xx2 = 0; xx2 < 64; ++xx2) {
            float2 a = rowz[xx2];
            float c = twc[m], s = tws[m];
            re += a.x * c + a.y * s;
            im += a.y * c - a.x * s;
            m = (m + kxa) & 63;
        }
        z3[(((size_t)(b * MP + kx) * MP + ky) * MK + kz) * CH + ci] = make_float2(re, im);
    }
}

// ---------------------------------------------------------------------------
// 4) per-mode 16x16 complex channel mix with corner weight selection
//    block = (b*24+kx)*24 + ky ; 4608 blocks x 192 threads (thread = o*12+kz)
__global__ __launch_bounds__(192) void k_mix(const float2* __restrict__ z3,
                                             const float* __restrict__ w1,
                                             const float* __restrict__ w2,
                                             const float* __restrict__ w3,
                                             const float* __restrict__ w4,
                                             float2* __restrict__ z4) {
    __shared__ float2 zs[12 * 17];     // [kz][ci] padded
    int tid = threadIdx.x;
    int blk = blockIdx.x;
    int ky = blk % MP;
    int t2 = blk / MP;
    int kx = t2 % MP;
    int b  = t2 / MP;
    const float2* src = z3 + (size_t)blk * (MK * CH);
    for (int i = tid; i < MK * CH; i += 192) {
        int kz = i >> 4, ii = i & 15;
        zs[kz * 17 + ii] = src[i];
    }
    __syncthreads();
    const float* wsel = (kx < 12) ? ((ky < 12) ? w1 : w3) : ((ky < 12) ? w2 : w4);
    int mx = (kx < 12) ? kx : kx - 12;
    int my = (ky < 12) ? ky : ky - 12;
    int kz = tid % MK, o = tid / MK;
    // w flat: ((((i*16+o)*12+mx)*12+my)*12+kz)*2
    const float* wp = wsel + (size_t)2 * (((o * 12 + mx) * 12 + my) * 12 + kz);
    float re = 0.f, im = 0.f;
    for (int i2 = 0; i2 < CH; ++i2) {
        float2 a = zs[kz * 17 + i2];
        float wr = wp[0], wi = wp[1];
        re += a.x * wr - a.y * wi;
        im += a.x * wi + a.y * wr;
        wp += 2 * 16 * 12 * 12 * 12;   // i-stride in floats
    }
    z4[(((size_t)(b * CH + o) * MP + ky) * MK + kz) * MP + kx] = make_float2(re, im);
}

// ---------------------------------------------------------------------------
// 5) inverse DFT over x: Z4[(bo*24+ky)][kz][kx] -> Z5[(bo*64+x)][kz][ky]
//    block = bo*24 + ky ; 3072 blocks x 256 threads
__global__ __launch_bounds__(256) void k_inv_x(const float2* __restrict__ z4,
                                               float2* __restrict__ z5) {
    __shared__ float2 zs[12 * 25];
    __shared__ float twc[64], tws[64];
    int tid = threadIdx.x;
    int blk = blockIdx.x;
    int ky = blk % MP, bo = blk / MP;
    build_tw(twc, tws, tid, 256);
    const float2* src = z4 + (size_t)blk * (MK * MP);
    for (int i = tid; i < MK * MP; i += 256) {
        int kz = i / MP, j = i % MP;
        zs[kz * 25 + j] = src[i];
    }
    __syncthreads();
    for (int idx = tid; idx < 64 * MK; idx += 256) {
        int xx = idx / MK, kz = idx % MK;
        const float2* rowz = zs + kz * 25;
        float re = 0.f, im = 0.f;
        for (int j = 0; j < MP; ++j) {
            int kxa = (j < 12) ? j : (j + 40);
            int m = (kxa * xx) & 63;
            float2 a = rowz[j];
            float c = twc[m], s = tws[m];
            re += a.x * c - a.y * s;            // a * (c + i s)
            im += a.x * s + a.y * c;
        }
        z5[((size_t)(bo * 64 + xx) * MK + kz) * MP + ky] = make_float2(re, im);
    }
}

// ---------------------------------------------------------------------------
// 6) inverse DFT over y: Z5[(bo*64+x)][kz][ky] -> Z6[((b*64+x)*64+y)][o][kz]
//    block = bo*64 + x ; 8192 blocks x 256 threads
__global__ __launch_bounds__(256) void k_inv_y(const float2* __restrict__ z5,
                                               float2* __restrict__ z6) {
    __shared__ float2 zs[12 * 25];
    __shared__ float twc[64], tws[64];
    int tid = threadIdx.x;
    int blk = blockIdx.x;
    int xx = blk & 63, bo = blk >> 6;
    int b = bo >> 4, o = bo & 15;
    build_tw(twc, tws, tid, 256);
    const float2* src = z5 + (size_t)blk * (MK * MP);
    for (int i = tid; i < MK * MP; i += 256) {
        int kz = i / MP, j = i % MP;
        zs[kz * 25 + j] = src[i];
    }
    __syncthreads();
    for (int idx = tid; idx < 64 * MK; idx += 256) {
        int yy = idx / MK, kz = idx % MK;
        const float2* rowz = zs + kz * 25;
        float re = 0.f, im = 0.f;
        for (int j = 0; j < MP; ++j) {
            int kya = (j < 12) ? j : (j + 40);
            int m = (kya * yy) & 63;
            float2 a = rowz[j];
            float c = twc[m], s = tws[m];
            re += a.x * c - a.y * s;
            im += a.x * s + a.y * c;
        }
        z6[(((size_t)((b * 64 + xx) * 64 + yy)) * CH + o) * MK + kz] = make_float2(re, im);
    }
}

// ---------------------------------------------------------------------------
// 7) irfft over t (c0=1, ck=2 hermitian weighting) + 1/64^3 + ReLU + 16x16 channel
//    mix + bias.  block = (b*64+x)*64+y ; 32768 blocks x 64 threads (thread = t)
__global__ __launch_bounds__(64) void k_inv_t_mix(const float2* __restrict__ z6,
                                                  const float* __restrict__ low,
                                                  const float* __restrict__ lob,
                                                  float* __restrict__ out) {
    __shared__ float2 zr[CH * MK];
    __shared__ float lws[CH * CH];
    __shared__ float lbs[CH];
    __shared__ float twc[64], tws[64];
    int tid = threadIdx.x;   // t
    int blk = blockIdx.x;
    build_tw(twc, tws, tid, 64);
    const float2* src = z6 + (size_t)blk * (CH * MK);
    for (int i = tid; i < CH * MK; i += 64) zr[i] = src[i];
    for (int i = tid; i < CH * CH; i += 64) lws[i] = low[i];
    if (tid < CH) lbs[tid] = lob[tid];
    __syncthreads();
    int yy = blk & 63;
    int xx = (blk >> 6) & 63;
    int b  = blk >> 12;
    const float inv = 1.0f / 262144.0f;   // 1/64^3
    float r[CH];
    for (int o = 0; o < CH; ++o) {
        float v = 0.f;
        for (int k = 0; k < MK; ++k) {
            float2 a = zr[o * MK + k];
            int m = (k * tid) & 63;
            float c = twc[m], s = tws[m];
            float term = a.x * c - a.y * s;   // Re(a * e^{+i theta})
            v += (k == 0) ? term : 2.f * term;
        }
        v *= inv;
        r[o] = (v > 0.f) ? v : 0.f;
    }
    for (int op = 0; op < CH; ++op) {
        float acc = lbs[op];
        for (int c2 = 0; c2 < CH; ++c2) acc += lws[op * CH + c2] * r[c2];
        out[(((size_t)(b * CH + op) * 64 + xx) * 64 + yy) * 64 + tid] = acc;
    }
}

// ---------------------------------------------------------------------------
extern "C" void kernel_launch(void* const* d_in, const int* in_sizes, int n_in,
                              void* d_out, int out_size, void* d_ws, size_t ws_size,
                              hipStream_t stream) {
    const float* x    = (const float*)d_in[0];
    const float* w1   = (const float*)d_in[1];
    const float* w2   = (const float*)d_in[2];
    const float* w3   = (const float*)d_in[3];
    const float* w4   = (const float*)d_in[4];
    const float* lo_w = (const float*)d_in[5];
    const float* lo_b = (const float*)d_in[6];
    float* out = (float*)d_out;
    char* ws = (char*)d_ws;

    // Workspace layout (bytes), with lifetime-based reuse (total 96 MB):
    //   Z1 [0, 50331648)        : fwd-t out, dead after k_fwd_y
    //   Z2 [50331648, 69206016) : dead after k_fwd_x
    //   Z3 [69206016, 76283904) : dead after k_mix
    //   Z4 [76283904, 83361792) : dead after k_inv_x
    //   Z5 = Z1's region        : born in k_inv_x
    //   Z6 [50331648, 100663296): born in k_inv_y (covers dead Z2/Z3/Z4)
    float2* z1 = (float2*)(ws);
    float2* z2 = (float2*)(ws + 50331648);
    float2* z3 = (float2*)(ws + 69206016);
    float2* z4 = (float2*)(ws + 76283904);
    float2* z5 = (float2*)(ws);
    float2* z6 = (float2*)(ws + 50331648);

    k_fwd_t   <<<dim3(8192),  dim3(256), 0, stream>>>(x, z1);
    k_fwd_y   <<<dim3(8192),  dim3(256), 0, stream>>>(z1, z2);
    k_fwd_x   <<<dim3(3072),  dim3(256), 0, stream>>>(z2, z3);
    k_mix     <<<dim3(4608),  dim3(192), 0, stream>>>(z3, w1, w2, w3, w4, z4);
    k_inv_x   <<<dim3(3072),  dim3(256), 0, stream>>>(z4, z5);
    k_inv_y   <<<dim3(8192),  dim3(256), 0, stream>>>(z5, z6);
    k_inv_t_mix<<<dim3(32768), dim3(64), 0, stream>>>(z6, lo_w, lo_b, out);
}

// Round 2
// 373.654 us; speedup vs baseline: 1.3286x; 1.3286x over previous
//
#include <hip/hip_runtime.h>
#include <cstddef>

#define TW64 0.09817477042468103f   // 2*pi/64

// complex MAC: acc += v * (c, s)   (w=(c,s) treated as a true complex number;
// forward kernels pass s = -sin so the same formula does e^{-i...})
#define CMAC(A, V)                                   \
    A.x = fmaf((V).x, c, A.x); A.x = fmaf(-(V).y, s, A.x); \
    A.y = fmaf((V).x, s, A.y); A.y = fmaf((V).y, c, A.y);

#define ROT()                                        \
    { float _t0 = s * ss; float _cn = fmaf(c, cs, -_t0); \
      s = fmaf(s, cs, c * ss); c = _cn; }

// ---------------------------------------------------------------------------
// 1) fwd t-DFT: x[blk= b*16c+..*64+x][yy][t] real -> z1[blk][kz][yy]
//    8192 blocks x 192 threads; thread = (k, yg), 4 yy per thread
__global__ __launch_bounds__(192) void k_fwd_t(const float* __restrict__ x,
                                               float2* __restrict__ z1) {
    __shared__ float xs[64 * 65];      // [yy][t] pad 65
    __shared__ float2 tmp[768];        // [k][yy]
    const int tid = threadIdx.x, blk = blockIdx.x;
    const float* src = x + (size_t)blk * 4096;
    for (int i = tid; i < 4096; i += 192) xs[(i >> 6) * 65 + (i & 63)] = src[i];
    __syncthreads();
    const int k = tid % 12, yg = tid / 12;      // yg 0..15
    const float* r0 = xs + (yg     ) * 65;
    const float* r1 = xs + (yg + 16) * 65;
    const float* r2 = xs + (yg + 32) * 65;
    const float* r3 = xs + (yg + 48) * 65;
    float ss, cs; __sincosf(-(float)k * TW64, &ss, &cs);   // (cos, -sin)
    float c = 1.f, s = 0.f;
    float2 a0 = {0.f,0.f}, a1 = {0.f,0.f}, a2 = {0.f,0.f}, a3 = {0.f,0.f};
    #pragma unroll 8
    for (int t = 0; t < 64; ++t) {
        float v0 = r0[t], v1 = r1[t], v2 = r2[t], v3 = r3[t];
        a0.x = fmaf(v0, c, a0.x); a0.y = fmaf(v0, s, a0.y);
        a1.x = fmaf(v1, c, a1.x); a1.y = fmaf(v1, s, a1.y);
        a2.x = fmaf(v2, c, a2.x); a2.y = fmaf(v2, s, a2.y);
        a3.x = fmaf(v3, c, a3.x); a3.y = fmaf(v3, s, a3.y);
        ROT();
    }
    tmp[k * 64 + yg     ] = a0;
    tmp[k * 64 + yg + 16] = a1;
    tmp[k * 64 + yg + 32] = a2;
    tmp[k * 64 + yg + 48] = a3;
    __syncthreads();
    float2* dst = z1 + (size_t)blk * 768;
    for (int i = tid; i < 768; i += 192) dst[i] = tmp[i];
}

// ---------------------------------------------------------------------------
// 2) fwd y-DFT: z1[(bc*64+xx)][kz][yy] -> z2[(bc*64+xx)][ky][kz]
//    blk = bc*32+xh (2 xx per block); 4096 blocks x 192 threads
//    thread = (sub, ky, g): one recurrence (step ky), 3 kz outputs
__global__ __launch_bounds__(192) void k_fwd_y(const float2* __restrict__ z1,
                                               float2* __restrict__ z2) {
    __shared__ float2 zs[2 * 792];     // [sub][kz][yy] pad 66
    __shared__ float2 tmp[576];        // [sub][ky][kz]
    const int tid = threadIdx.x, blk = blockIdx.x;
    const float2* src = z1 + (size_t)blk * 1536;
    for (int i = tid; i < 1536; i += 192) {
        int sb = i / 768, rem = i % 768;
        zs[sb * 792 + (rem >> 6) * 66 + (rem & 63)] = src[i];
    }
    __syncthreads();
    const int sub = tid / 96, r = tid % 96;
    const int ky = r % 24, g = r / 24;                 // g 0..3
    const int kya = (ky < 12) ? ky : ky + 40;
    const float2* p0 = zs + sub * 792 + (g    ) * 66;
    const float2* p1 = zs + sub * 792 + (g + 4) * 66;
    const float2* p2 = zs + sub * 792 + (g + 8) * 66;
    float ss, cs; __sincosf(-(float)kya * TW64, &ss, &cs);
    float c = 1.f, s = 0.f;
    float2 a0 = {0.f,0.f}, a1 = {0.f,0.f}, a2 = {0.f,0.f};
    #pragma unroll 4
    for (int yy = 0; yy < 64; ++yy) {
        float2 v0 = p0[yy], v1 = p1[yy], v2 = p2[yy];
        CMAC(a0, v0); CMAC(a1, v1); CMAC(a2, v2);
        ROT();
    }
    tmp[sub * 288 + ky * 12 + g    ] = a0;
    tmp[sub * 288 + ky * 12 + g + 4] = a1;
    tmp[sub * 288 + ky * 12 + g + 8] = a2;
    __syncthreads();
    float2* dst = z2 + (size_t)blk * 576;
    for (int i = tid; i < 576; i += 192) dst[i] = tmp[i];
}

// ---------------------------------------------------------------------------
// 3) fwd x-DFT: z2[(bc*64+xx)][ky][kz] -> z3[bc][kx][ky][kz]
//    blk = bc*12+kyh (2 ky per block); 1536 blocks x 192 threads
__global__ __launch_bounds__(192) void k_fwd_x(const float2* __restrict__ z2,
                                               float2* __restrict__ z3) {
    __shared__ float2 zs[2 * 792];     // [sub(ky)][kz][xx] pad 66
    __shared__ float2 tmp[576];        // [kx][sub][kz]
    const int tid = threadIdx.x, blk = blockIdx.x;
    const int kyh = blk % 12, bc = blk / 12;
    const float2* srcb = z2 + (size_t)bc * 18432 + (size_t)kyh * 24;
    for (int i = tid; i < 1536; i += 192) {
        int xx = i / 24, r2 = i % 24;
        int sb = r2 / 12, kz = r2 % 12;
        zs[sb * 792 + kz * 66 + xx] = srcb[(size_t)xx * 288 + sb * 12 + kz];
    }
    __syncthreads();
    const int sub = tid / 96, r = tid % 96;
    const int kx = r % 24, g = r / 24;
    const int kxa = (kx < 12) ? kx : kx + 40;
    const float2* p0 = zs + sub * 792 + (g    ) * 66;
    const float2* p1 = zs + sub * 792 + (g + 4) * 66;
    const float2* p2 = zs + sub * 792 + (g + 8) * 66;
    float ss, cs; __sincosf(-(float)kxa * TW64, &ss, &cs);
    float c = 1.f, s = 0.f;
    float2 a0 = {0.f,0.f}, a1 = {0.f,0.f}, a2 = {0.f,0.f};
    #pragma unroll 4
    for (int xx = 0; xx < 64; ++xx) {
        float2 v0 = p0[xx], v1 = p1[xx], v2 = p2[xx];
        CMAC(a0, v0); CMAC(a1, v1); CMAC(a2, v2);
        ROT();
    }
    tmp[kx * 24 + sub * 12 + g    ] = a0;
    tmp[kx * 24 + sub * 12 + g + 4] = a1;
    tmp[kx * 24 + sub * 12 + g + 8] = a2;
    __syncthreads();
    float2* dstb = z3 + (size_t)bc * 6912 + (size_t)kyh * 24;
    for (int i = tid; i < 576; i += 192) dstb[(i / 24) * 288 + (i % 24)] = tmp[i];
}

// ---------------------------------------------------------------------------
// 4) channel mix: z3[b*16+ci][kx][ky][kz] -> z4[(b*16+o)][ky][kx][kz]
//    blk = kx*24+ky (576 blocks) x 192 threads; weights in regs, b-loop inside
__global__ __launch_bounds__(192) void k_mix(const float2* __restrict__ z3,
                                             const float* __restrict__ w1,
                                             const float* __restrict__ w2,
                                             const float* __restrict__ w3,
                                             const float* __restrict__ w4,
                                             float2* __restrict__ z4) {
    __shared__ float2 zs[12 * 17];     // [kz][ci] pad 17
    const int tid = threadIdx.x, blk = blockIdx.x;
    const int ky = blk % 24, kx = blk / 24;
    const int o = tid / 12, kz = tid % 12;
    const float* wsel = (kx < 12) ? ((ky < 12) ? w1 : w3) : ((ky < 12) ? w2 : w4);
    const int mx = (kx < 12) ? kx : kx - 12;
    const int my = (ky < 12) ? ky : ky - 12;
    const float* wp = wsel + (size_t)2 * (((o * 12 + mx) * 12 + my) * 12 + kz);
    float wr[16], wi[16];
    #pragma unroll
    for (int i = 0; i < 16; ++i) {
        wr[i] = wp[0]; wi[i] = wp[1];
        wp += 2 * 16 * 12 * 12 * 12;
    }
    for (int b = 0; b < 8; ++b) {
        __syncthreads();
        {   // loader view: tid -> (ci, kz2)
            int ci = tid / 12, kz2 = tid % 12;
            zs[kz2 * 17 + ci] =
                z3[((size_t)(b * 16 + ci) * 24 + kx) * 288 + ky * 12 + kz2];
        }
        __syncthreads();
        float re = 0.f, im = 0.f;
        #pragma unroll
        for (int i = 0; i < 16; ++i) {
            float2 a = zs[kz * 17 + i];
            re = fmaf(a.x, wr[i], re); re = fmaf(-a.y, wi[i], re);
            im = fmaf(a.x, wi[i], im); im = fmaf(a.y, wr[i], im);
        }
        z4[((size_t)(b * 16 + o) * 24 + ky) * 288 + kx * 12 + kz] =
            make_float2(re, im);
    }
}

// ---------------------------------------------------------------------------
// 5) inv x-DFT: z4[bo][ky][kx][kz] -> z5[bo][ky][kz][xx]
//    blk = bo*24+ky (3072) x 256 threads; thread = (xx, g): 1 recurrence, 3 kz
__global__ __launch_bounds__(256) void k_inv_x(const float2* __restrict__ z4,
                                               float2* __restrict__ z5) {
    __shared__ float2 zs[12 * 26];     // [kz][kx] pad 26
    const int tid = threadIdx.x, blk = blockIdx.x;
    const float2* src = z4 + (size_t)blk * 288;
    for (int i = tid; i < 288; i += 256) {
        int kx = i / 12, kz = i % 12;
        zs[kz * 26 + kx] = src[i];
    }
    __syncthreads();
    const int xx = tid & 63, g = tid >> 6;
    const float2* p0 = zs + (g    ) * 26;
    const float2* p1 = zs + (g + 4) * 26;
    const float2* p2 = zs + (g + 8) * 26;
    float ss, cs; __sincosf((float)xx * TW64, &ss, &cs);   // (cos, +sin)
    float c = 1.f, s = 0.f;
    float2 a0 = {0.f,0.f}, a1 = {0.f,0.f}, a2 = {0.f,0.f};
    #pragma unroll 4
    for (int j = 0; j < 12; ++j) {
        float2 v0 = p0[j], v1 = p1[j], v2 = p2[j];
        CMAC(a0, v0); CMAC(a1, v1); CMAC(a2, v2);
        ROT();
    }
    { float sh, ch; __sincosf((float)((52 * xx) & 63) * TW64, &sh, &ch);
      c = ch; s = sh; }
    #pragma unroll 4
    for (int j = 12; j < 24; ++j) {
        float2 v0 = p0[j], v1 = p1[j], v2 = p2[j];
        CMAC(a0, v0); CMAC(a1, v1); CMAC(a2, v2);
        ROT();
    }
    float2* dst = z5 + (size_t)blk * 768;
    dst[(g    ) * 64 + xx] = a0;
    dst[(g + 4) * 64 + xx] = a1;
    dst[(g + 8) * 64 + xx] = a2;
}

// ---------------------------------------------------------------------------
// 6) inv y-DFT: z5[bo][ky][kz][xx] -> z6[bo][xx][yy][kz]
//    blk = bo*64+xx (8192) x 256 threads
__global__ __launch_bounds__(256) void k_inv_y(const float2* __restrict__ z5,
                                               float2* __restrict__ z6) {
    __shared__ float2 zs[12 * 26];     // [kz][ky]
    __shared__ float2 tmp[768];        // [yy][kz]
    const int tid = threadIdx.x, blk = blockIdx.x;
    const int xx = blk & 63, bo = blk >> 6;
    for (int i = tid; i < 288; i += 256) {
        int ky = i / 12, kz = i % 12;
        zs[kz * 26 + ky] = z5[((size_t)bo * 24 + ky) * 768 + kz * 64 + xx];
    }
    __syncthreads();
    const int yy = tid & 63, g = tid >> 6;
    const float2* p0 = zs + (g    ) * 26;
    const float2* p1 = zs + (g + 4) * 26;
    const float2* p2 = zs + (g + 8) * 26;
    float ss, cs; __sincosf((float)yy * TW64, &ss, &cs);
    float c = 1.f, s = 0.f;
    float2 a0 = {0.f,0.f}, a1 = {0.f,0.f}, a2 = {0.f,0.f};
    #pragma unroll 4
    for (int j = 0; j < 12; ++j) {
        float2 v0 = p0[j], v1 = p1[j], v2 = p2[j];
        CMAC(a0, v0); CMAC(a1, v1); CMAC(a2, v2);
        ROT();
    }
    { float sh, ch; __sincosf((float)((52 * yy) & 63) * TW64, &sh, &ch);
      c = ch; s = sh; }
    #pragma unroll 4
    for (int j = 12; j < 24; ++j) {
        float2 v0 = p0[j], v1 = p1[j], v2 = p2[j];
        CMAC(a0, v0); CMAC(a1, v1); CMAC(a2, v2);
        ROT();
    }
    tmp[yy * 12 + g    ] = a0;
    tmp[yy * 12 + g + 4] = a1;
    tmp[yy * 12 + g + 8] = a2;
    __syncthreads();
    float2* dst = z6 + (size_t)blk * 768;
    for (int i = tid; i < 768; i += 256) dst[i] = tmp[i];
}

// ---------------------------------------------------------------------------
// 7) irfft over t + 1/64^3 + ReLU + 16x16 channel mix + bias
//    blk = b*1024 + xx*16 + yq (8192) x 256 threads (4 yy per block, thread=(sub,t))
__global__ __launch_bounds__(256) void k_inv_t_mix(const float2* __restrict__ z6,
                                                   const float* __restrict__ low,
                                                   const float* __restrict__ lob,
                                                   float* __restrict__ out) {
    __shared__ float2 zr[4 * 192];     // [sub][o][kz]
    __shared__ float lws[256];
    __shared__ float lbs[16];
    const int tid = threadIdx.x, blk = blockIdx.x;
    const int yq = blk & 15, xx = (blk >> 4) & 63, b = blk >> 10;
    for (int i = tid; i < 768; i += 256) {
        int sb = i / 192, rem = i % 192;
        int o = rem / 12, kz = rem % 12;
        int yy = yq * 4 + sb;
        zr[i] = z6[((size_t)(b * 16 + o) * 4096 + xx * 64 + yy) * 12 + kz];
    }
    lws[tid & 255] = low[tid & 255];
    if (tid < 16) lbs[tid] = lob[tid];
    __syncthreads();
    const int sub = tid >> 6, t = tid & 63;
    const float2* zp = zr + sub * 192;
    float bs, bc; __sincosf((float)t * TW64, &bs, &bc);
    const float inv = 1.0f / 262144.0f;
    float cw[12], sw[12];
    cw[0] = inv; sw[0] = 0.f;
    {
        float c = bc, s = bs;
        #pragma unroll
        for (int k = 1; k < 12; ++k) {
            cw[k] = 2.f * inv * c; sw[k] = 2.f * inv * s;
            float cn = c * bc - s * bs;
            s = fmaf(s, bc, c * bs);
            c = cn;
        }
    }
    float r[16];
    #pragma unroll
    for (int o = 0; o < 16; ++o) {
        float v = 0.f;
        #pragma unroll
        for (int k = 0; k < 12; ++k) {
            float2 a = zp[o * 12 + k];
            v = fmaf(a.x, cw[k], v);
            v = fmaf(-a.y, sw[k], v);
        }
        r[o] = fmaxf(v, 0.f);
    }
    const int yy = yq * 4 + sub;
    const size_t obase = (size_t)b * 16 * 262144 + (size_t)xx * 4096
                       + (size_t)yy * 64 + t;
    #pragma unroll
    for (int op = 0; op < 16; ++op) {
        float acc = lbs[op];
        #pragma unroll
        for (int c2 = 0; c2 < 16; ++c2) acc = fmaf(lws[op * 16 + c2], r[c2], acc);
        out[obase + (size_t)op * 262144] = acc;
    }
}

// ---------------------------------------------------------------------------
extern "C" void kernel_launch(void* const* d_in, const int* in_sizes, int n_in,
                              void* d_out, int out_size, void* d_ws, size_t ws_size,
                              hipStream_t stream) {
    const float* x    = (const float*)d_in[0];
    const float* w1   = (const float*)d_in[1];
    const float* w2   = (const float*)d_in[2];
    const float* w3   = (const float*)d_in[3];
    const float* w4   = (const float*)d_in[4];
    const float* lo_w = (const float*)d_in[5];
    const float* lo_b = (const float*)d_in[6];
    float* out = (float*)d_out;
    char* ws = (char*)d_ws;

    // Workspace (bytes), lifetime-reused, total 96 MB:
    //   z1 [0, 50331648)          dead after k_fwd_y
    //   z2 [50331648, 69206016)   dead after k_fwd_x
    //   z3 [69206016, 76283904)   dead after k_mix
    //   z4 [76283904, 83361792)   dead after k_inv_x
    //   z5 = z1 region (18.9 MB)  born in k_inv_x
    //   z6 [50331648, 100663296)  born in k_inv_y
    float2* z1 = (float2*)(ws);
    float2* z2 = (float2*)(ws + 50331648);
    float2* z3 = (float2*)(ws + 69206016);
    float2* z4 = (float2*)(ws + 76283904);
    float2* z5 = (float2*)(ws);
    float2* z6 = (float2*)(ws + 50331648);

    k_fwd_t    <<<dim3(8192), dim3(192), 0, stream>>>(x, z1);
    k_fwd_y    <<<dim3(4096), dim3(192), 0, stream>>>(z1, z2);
    k_fwd_x    <<<dim3(1536), dim3(192), 0, stream>>>(z2, z3);
    k_mix      <<<dim3(576),  dim3(192), 0, stream>>>(z3, w1, w2, w3, w4, z4);
    k_inv_x    <<<dim3(3072), dim3(256), 0, stream>>>(z4, z5);
    k_inv_y    <<<dim3(8192), dim3(256), 0, stream>>>(z5, z6);
    k_inv_t_mix<<<dim3(8192), dim3(256), 0, stream>>>(z6, lo_w, lo_b, out);
}